// Round 2
// baseline (2832.768 us; speedup 1.0000x reference)
//
#include <hip/hip_runtime.h>
#include <hip/hip_bf16.h>
#include <math.h>

#define S_LEN 2048
#define C_DIM 1024
#define NH    16
#define HD    64
#define TOPK  128

typedef __attribute__((ext_vector_type(8))) short s16x8;
typedef __attribute__((ext_vector_type(4))) float f32x4;

__device__ __forceinline__ unsigned fkey(float f) {
    unsigned u = __float_as_uint(f);
    return (u & 0x80000000u) ? ~u : (u | 0x80000000u);
}

// ---------------- f32 -> bf16 convert ----------------
__global__ void cvt_f32_bf16(const float* __restrict__ in, __hip_bfloat16* __restrict__ out, int n) {
    int idx = (blockIdx.x * blockDim.x + threadIdx.x) * 4;
    if (idx + 3 < n) {
        float4 v = *(const float4*)(in + idx);
        out[idx + 0] = __float2bfloat16(v.x);
        out[idx + 1] = __float2bfloat16(v.y);
        out[idx + 2] = __float2bfloat16(v.z);
        out[idx + 3] = __float2bfloat16(v.w);
    }
}

// ---------------- GEMM: C[M][N] = A[M][K] * B[N][K]^T (bf16 in, f32 out) ----------------
// 128x128 tile, 4 waves (2x2), each wave 64x64 via 4x4 frags of 16x16x32 MFMA.
__global__ __launch_bounds__(256) void gemm_bt(const __hip_bfloat16* __restrict__ A,
                                               const __hip_bfloat16* __restrict__ B,
                                               float* __restrict__ C,
                                               int M, int N, int K)
{
    __shared__ short As[128][40];  // +8 pad: breaks 8-way bank conflict on b128 frag reads
    __shared__ short Bs[128][40];
    const int bm = blockIdx.y * 128;
    const int bn = blockIdx.x * 128;
    const int tid = threadIdx.x;
    const int lane = tid & 63;
    const int wave = tid >> 6;
    const int wm = (wave >> 1) * 64;
    const int wn = (wave & 1) * 64;

    f32x4 acc[4][4] = {};

    const int srow = tid >> 1;        // 0..127
    const int scol = (tid & 1) * 16;  // 0 or 16

    const int fr = lane & 15;
    const int fk = (lane >> 4) * 8;

    for (int k0 = 0; k0 < K; k0 += 32) {
        const short* ga = (const short*)A + (size_t)(bm + srow) * K + k0 + scol;
        const short* gb = (const short*)B + (size_t)(bn + srow) * K + k0 + scol;
        __syncthreads();
        *(s16x8*)&As[srow][scol]     = *(const s16x8*)ga;
        *(s16x8*)&As[srow][scol + 8] = *(const s16x8*)(ga + 8);
        *(s16x8*)&Bs[srow][scol]     = *(const s16x8*)gb;
        *(s16x8*)&Bs[srow][scol + 8] = *(const s16x8*)(gb + 8);
        __syncthreads();

        s16x8 af[4], bfr[4];
        #pragma unroll
        for (int m = 0; m < 4; ++m) af[m]  = *(const s16x8*)&As[wm + m * 16 + fr][fk];
        #pragma unroll
        for (int n = 0; n < 4; ++n) bfr[n] = *(const s16x8*)&Bs[wn + n * 16 + fr][fk];
        #pragma unroll
        for (int m = 0; m < 4; ++m)
            #pragma unroll
            for (int n = 0; n < 4; ++n)
                acc[m][n] = __builtin_amdgcn_mfma_f32_16x16x32_bf16(af[m], bfr[n], acc[m][n], 0, 0, 0);
    }

    const int cr = (lane >> 4) * 4;
    const int cc = lane & 15;
    #pragma unroll
    for (int m = 0; m < 4; ++m)
        #pragma unroll
        for (int n = 0; n < 4; ++n)
            #pragma unroll
            for (int j = 0; j < 4; ++j) {
                int row = bm + wm + m * 16 + cr + j;
                int col = bn + wn + n * 16 + cc;
                C[(size_t)row * N + col] = acc[m][n][j];
            }
}

// ---------------- RoPE + L2-normalize + head split ----------------
// one wave per (h,s); lane = dim
__global__ __launch_bounds__(256) void rope_norm(const float* __restrict__ qkv,
                                                 float* __restrict__ qh,
                                                 float* __restrict__ kh,
                                                 float* __restrict__ vh)
{
    const int gw = blockIdx.x * 4 + (threadIdx.x >> 6);
    const int lane = threadIdx.x & 63;
    const int h = gw >> 11;   // /2048
    const int s = gw & 2047;
    const float* base = qkv + (size_t)s * (3 * C_DIM);
    float qx = base[h * HD + lane];
    float kx = base[C_DIM + h * HD + lane];
    float vx = base[2 * C_DIM + h * HD + lane];

    // interleaved RoPE: pair (2i, 2i+1), angle = s * 10000^{-2i/64}
    const int i = lane >> 1;
    const float invf = expf(-(float)(2 * i) * (9.210340371976184f / 64.f));
    const float ang = (float)s * invf;
    float sn, cs;
    sincosf(ang, &sn, &cs);
    float qp = __shfl_xor(qx, 1);
    float kp = __shfl_xor(kx, 1);
    const float sgn = (lane & 1) ? 1.f : -1.f;  // even lane: -odd*sin ; odd lane: +even*sin
    float qr = qx * cs + sgn * qp * sn;
    float kr = kx * cs + sgn * kp * sn;

    float s2q = qr * qr, s2k = kr * kr;
    #pragma unroll
    for (int off = 32; off > 0; off >>= 1) {
        s2q += __shfl_xor(s2q, off);
        s2k += __shfl_xor(s2k, off);
    }
    qr = qr / fmaxf(sqrtf(s2q), 1e-12f);
    kr = kr / fmaxf(sqrtf(s2k), 1e-12f);

    size_t o = ((size_t)h * S_LEN + s) * HD + lane;
    qh[o] = qr; kh[o] = kr; vh[o] = vx;
}

// ---------------- attention: one block per (q,h) row ----------------
// scores -> exact top-128 (radix select, index-ordered ties) -> softmax -> PV
__global__ __launch_bounds__(256) void attn_row(const float* __restrict__ qh,
                                                const float* __restrict__ kh,
                                                const float* __restrict__ vh,
                                                __hip_bfloat16* __restrict__ yb)
{
    __shared__ float sc[S_LEN];
    __shared__ float qv[HD];
    __shared__ unsigned hist[256];
    __shared__ int klist[TOPK];
    __shared__ float plist[TOPK];
    __shared__ float accs[4][HD];
    __shared__ float wred[4];
    __shared__ unsigned s_prefix;
    __shared__ int s_need, s_eqtot, s_cnt;
    __shared__ float s_sum;

    const int q = blockIdx.x;
    const int h = blockIdx.y;
    const int L = q + 1;
    const int tid = threadIdx.x;
    const int lane = tid & 63;
    const int wv = tid >> 6;

    if (tid < HD) qv[tid] = qh[((size_t)h * S_LEN + q) * HD + tid];
    if (tid == 0) { s_cnt = 0; s_sum = 0.f; s_prefix = 0u; s_need = TOPK; }
    __syncthreads();

    // phase 1: scores (f32 dot, /sqrt(64))
    for (int k = tid; k < L; k += 256) {
        const float4* kr = (const float4*)(kh + ((size_t)h * S_LEN + k) * HD);
        float acc = 0.f;
        #pragma unroll
        for (int j = 0; j < 16; ++j) {
            float4 kvv = kr[j];
            acc += qv[4 * j + 0] * kvv.x + qv[4 * j + 1] * kvv.y
                 + qv[4 * j + 2] * kvv.z + qv[4 * j + 3] * kvv.w;
        }
        sc[k] = acc * 0.125f;
    }
    __syncthreads();

    // phase 2: row max
    float pm = -3.0e38f;
    for (int k = tid; k < L; k += 256) pm = fmaxf(pm, sc[k]);
    #pragma unroll
    for (int off = 32; off > 0; off >>= 1) pm = fmaxf(pm, __shfl_xor(pm, off));
    if (lane == 0) wred[wv] = pm;
    __syncthreads();
    const float m = fmaxf(fmaxf(wred[0], wred[1]), fmaxf(wred[2], wred[3]));

    // phase 3: radix-select 128th-largest threshold key
    unsigned T = 0u; int takeEq = 0, eqTot = 0;
    if (L > TOPK) {
        for (int pass = 0; pass < 4; ++pass) {
            const int shift = 24 - pass * 8;
            hist[tid] = 0u;
            __syncthreads();
            const unsigned pref = s_prefix;
            for (int k = tid; k < L; k += 256) {
                unsigned u = fkey(sc[k]);
                if (pass == 0 || (u >> (shift + 8)) == pref)
                    atomicAdd(&hist[(u >> shift) & 255u], 1u);
            }
            __syncthreads();
            if (tid == 0) {
                int need = s_need, accd = 0, d = 255;
                for (; d > 0; --d) {
                    int c = (int)hist[d];
                    if (accd + c >= need) break;
                    accd += c;
                }
                s_prefix = (pref << 8) | (unsigned)d;
                s_need = need - accd;
                if (pass == 3) s_eqtot = (int)hist[d];
            }
            __syncthreads();
        }
        T = s_prefix; takeEq = s_need; eqTot = s_eqtot;
    }

    // phase 4: compact kept entries, exp, sum
    if (L <= TOPK) {
        for (int k = tid; k < L; k += 256) {
            float p = expf(sc[k] - m);
            int slot = atomicAdd(&s_cnt, 1);
            klist[slot] = k; plist[slot] = p;
            atomicAdd(&s_sum, p);
        }
    } else {
        for (int k = tid; k < L; k += 256) {
            unsigned u = fkey(sc[k]);
            bool keep = (u > T);
            if (!keep && u == T) {
                if (takeEq == eqTot) keep = true;  // common case: no boundary tie
                else {
                    int r = 0;  // rare exact-tie: rank by index like lax.top_k
                    for (int j = 0; j < k; ++j) r += (fkey(sc[j]) == T);
                    keep = (r < takeEq);
                }
            }
            if (keep) {
                float p = expf(sc[k] - m);
                int slot = atomicAdd(&s_cnt, 1);
                klist[slot] = k; plist[slot] = p;
                atomicAdd(&s_sum, p);
            }
        }
    }
    __syncthreads();

    // phase 5: PV (4 wave-groups over kept list, lane = dim)
    const int cnt = s_cnt;
    const float inv = 1.0f / s_sum;
    float acc = 0.f;
    for (int i = wv; i < cnt; i += 4)
        acc += plist[i] * vh[((size_t)h * S_LEN + klist[i]) * HD + lane];
    accs[wv][lane] = acc;
    __syncthreads();
    if (tid < HD) {
        float y = (accs[0][tid] + accs[1][tid] + accs[2][tid] + accs[3][tid]) * inv;
        yb[(size_t)q * C_DIM + h * HD + tid] = __float2bfloat16(y);
    }
}

// ---------------- launch ----------------
extern "C" void kernel_launch(void* const* d_in, const int* in_sizes, int n_in,
                              void* d_out, int out_size, void* d_ws, size_t ws_size,
                              hipStream_t stream)
{
    const float* x      = (const float*)d_in[0];
    const float* w_qkv  = (const float*)d_in[1];
    const float* w_proj = (const float*)d_in[2];
    float* out = (float*)d_out;

    char* ws = (char*)d_ws;
    size_t off = 0;
    auto alloc = [&](size_t bytes) -> void* {
        void* p = ws + off;
        off += (bytes + 255) & ~(size_t)255;
        return p;
    };
    __hip_bfloat16* xb  = (__hip_bfloat16*)alloc((size_t)S_LEN * C_DIM * 2);
    __hip_bfloat16* wqb = (__hip_bfloat16*)alloc((size_t)3 * C_DIM * C_DIM * 2);
    __hip_bfloat16* wpb = (__hip_bfloat16*)alloc((size_t)C_DIM * C_DIM * 2);
    float* qkvf = (float*)alloc((size_t)S_LEN * 3 * C_DIM * 4);
    float* qh   = (float*)alloc((size_t)NH * S_LEN * HD * 4);
    float* kh   = (float*)alloc((size_t)NH * S_LEN * HD * 4);
    float* vh   = (float*)alloc((size_t)NH * S_LEN * HD * 4);
    __hip_bfloat16* yb = (__hip_bfloat16*)alloc((size_t)S_LEN * C_DIM * 2);

    int n1 = S_LEN * C_DIM, n2 = 3 * C_DIM * C_DIM, n3 = C_DIM * C_DIM;
    cvt_f32_bf16<<<n1 / 4 / 256, 256, 0, stream>>>(x, xb, n1);
    cvt_f32_bf16<<<n2 / 4 / 256, 256, 0, stream>>>(w_qkv, wqb, n2);
    cvt_f32_bf16<<<n3 / 4 / 256, 256, 0, stream>>>(w_proj, wpb, n3);

    gemm_bt<<<dim3(3 * C_DIM / 128, S_LEN / 128), 256, 0, stream>>>(xb, wqb, qkvf, S_LEN, 3 * C_DIM, C_DIM);

    rope_norm<<<NH * S_LEN / 4, 256, 0, stream>>>(qkvf, qh, kh, vh);

    attn_row<<<dim3(S_LEN, NH), 256, 0, stream>>>(qh, kh, vh, yb);

    gemm_bt<<<dim3(C_DIM / 128, S_LEN / 128), 256, 0, stream>>>(yb, wpb, out, S_LEN, C_DIM, C_DIM);
}

// Round 3
// 690.689 us; speedup vs baseline: 4.1014x; 4.1014x over previous
//
#include <hip/hip_runtime.h>
#include <hip/hip_bf16.h>
#include <math.h>

#define S_LEN 2048
#define C_DIM 1024
#define NH    16
#define HD    64
#define TOPK  128

typedef __attribute__((ext_vector_type(8))) short s16x8;
typedef __attribute__((ext_vector_type(4))) float f32x4;

#define KSCALE 250000.0f
#define KINV   (1.0f / 250000.0f)
#define KOFF   0.13f

// ---------------- f32 -> bf16 convert ----------------
__global__ void cvt_f32_bf16(const float* __restrict__ in, __hip_bfloat16* __restrict__ out, int n) {
    int idx = (blockIdx.x * blockDim.x + threadIdx.x) * 4;
    if (idx + 3 < n) {
        float4 v = *(const float4*)(in + idx);
        out[idx + 0] = __float2bfloat16(v.x);
        out[idx + 1] = __float2bfloat16(v.y);
        out[idx + 2] = __float2bfloat16(v.z);
        out[idx + 3] = __float2bfloat16(v.w);
    }
}

// ---------------- GEMM (m97 structure): C[M][N] = A[M][K] * B[N][K]^T ----------------
// 128x128 tile, BK=32, linear LDS, global_load_lds width=16, 4 waves 2x2, 16x16x32 MFMA.
typedef const __attribute__((address_space(1))) unsigned int* gp32;
typedef __attribute__((address_space(3))) unsigned int* lp32;

__global__ __launch_bounds__(256) void gemm_bt(const __hip_bfloat16* __restrict__ A,
                                               const __hip_bfloat16* __restrict__ B,
                                               float* __restrict__ C,
                                               int M, int N, int K)
{
    __shared__ short As[128 * 32];
    __shared__ short Bs[128 * 32];
    const int bm = blockIdx.y * 128;
    const int bn = blockIdx.x * 128;
    const int tid = threadIdx.x;
    const int lane = tid & 63;
    const int wave = tid >> 6;
    const int wm = (wave >> 1) * 64;
    const int wn = (wave & 1) * 64;

    f32x4 acc[4][4] = {};

    const int srow = tid >> 2;        // 0..63
    const int scol = (tid & 3) * 8;   // elem offset within 32-elem row
    const int fr = lane & 15;
    const int fk = (lane >> 4) * 8;

    const short* Ab = (const short*)A;
    const short* Bb = (const short*)B;

    for (int k0 = 0; k0 < K; k0 += 32) {
        __syncthreads();
        // stage A: rows [bm, bm+128), 32 k-elems, two 4KB instrs (rows 0-63, 64-127)
        __builtin_amdgcn_global_load_lds((gp32)(Ab + (size_t)(bm + srow) * K + k0 + scol),
                                         (lp32)((char*)As + tid * 16), 16, 0, 0);
        __builtin_amdgcn_global_load_lds((gp32)(Ab + (size_t)(bm + 64 + srow) * K + k0 + scol),
                                         (lp32)((char*)As + 4096 + tid * 16), 16, 0, 0);
        __builtin_amdgcn_global_load_lds((gp32)(Bb + (size_t)(bn + srow) * K + k0 + scol),
                                         (lp32)((char*)Bs + tid * 16), 16, 0, 0);
        __builtin_amdgcn_global_load_lds((gp32)(Bb + (size_t)(bn + 64 + srow) * K + k0 + scol),
                                         (lp32)((char*)Bs + 4096 + tid * 16), 16, 0, 0);
        __syncthreads();

        s16x8 af[4], bfr[4];
        #pragma unroll
        for (int m = 0; m < 4; ++m) af[m]  = *(const s16x8*)&As[(wm + m * 16 + fr) * 32 + fk];
        #pragma unroll
        for (int n = 0; n < 4; ++n) bfr[n] = *(const s16x8*)&Bs[(wn + n * 16 + fr) * 32 + fk];
        #pragma unroll
        for (int m = 0; m < 4; ++m)
            #pragma unroll
            for (int n = 0; n < 4; ++n)
                acc[m][n] = __builtin_amdgcn_mfma_f32_16x16x32_bf16(af[m], bfr[n], acc[m][n], 0, 0, 0);
    }

    const int cr = (lane >> 4) * 4;
    const int cc = lane & 15;
    #pragma unroll
    for (int m = 0; m < 4; ++m)
        #pragma unroll
        for (int n = 0; n < 4; ++n)
            #pragma unroll
            for (int j = 0; j < 4; ++j) {
                int row = bm + wm + m * 16 + cr + j;
                int col = bn + wn + n * 16 + cc;
                C[(size_t)row * N + col] = acc[m][n][j];
            }
}

// ---------------- RoPE + L2-normalize + head split (bf16 hi/lo for q,k; f32 v) -------
__global__ __launch_bounds__(256) void rope_norm(const float* __restrict__ qkv,
                                                 __hip_bfloat16* __restrict__ qhi,
                                                 __hip_bfloat16* __restrict__ qlo,
                                                 __hip_bfloat16* __restrict__ khi,
                                                 __hip_bfloat16* __restrict__ klo,
                                                 float* __restrict__ vh)
{
    const int gw = blockIdx.x * 4 + (threadIdx.x >> 6);
    const int lane = threadIdx.x & 63;
    const int h = gw >> 11;   // /2048
    const int s = gw & 2047;
    const float* base = qkv + (size_t)s * (3 * C_DIM);
    float qx = base[h * HD + lane];
    float kx = base[C_DIM + h * HD + lane];
    float vx = base[2 * C_DIM + h * HD + lane];

    const int i = lane >> 1;
    const float invf = expf(-(float)(2 * i) * (9.210340371976184f / 64.f));
    const float ang = (float)s * invf;
    float sn, cs;
    sincosf(ang, &sn, &cs);
    float qp = __shfl_xor(qx, 1);
    float kp = __shfl_xor(kx, 1);
    const float sgn = (lane & 1) ? 1.f : -1.f;
    float qr = qx * cs + sgn * qp * sn;
    float kr = kx * cs + sgn * kp * sn;

    float s2q = qr * qr, s2k = kr * kr;
    #pragma unroll
    for (int off = 32; off > 0; off >>= 1) {
        s2q += __shfl_xor(s2q, off);
        s2k += __shfl_xor(s2k, off);
    }
    qr = qr / fmaxf(sqrtf(s2q), 1e-12f);
    kr = kr / fmaxf(sqrtf(s2k), 1e-12f);

    size_t o = ((size_t)h * S_LEN + s) * HD + lane;
    __hip_bfloat16 qh_ = __float2bfloat16(qr);
    __hip_bfloat16 kh_ = __float2bfloat16(kr);
    qhi[o] = qh_; qlo[o] = __float2bfloat16(qr - __bfloat162float(qh_));
    khi[o] = kh_; klo[o] = __float2bfloat16(kr - __bfloat162float(kh_));
    vh[o] = vx;
}

// ---------------- wave helpers ----------------
__device__ __forceinline__ unsigned wave_prefix_incl(unsigned v, int lane) {
    #pragma unroll
    for (int off = 1; off < 64; off <<= 1) {
        unsigned t = __shfl_up(v, off);
        v += (lane >= off) ? t : 0u;
    }
    return v;
}

// find threshold byte B (descending) s.t. count(byte>B) < need <= count(byte>=B)
__device__ __forceinline__ void find_byte(const unsigned* hist256, int need, int lane,
                                          int& B, int& needRem, int& eqc)
{
    uint4 b = *(const uint4*)&hist256[lane * 4];
    unsigned sl = b.x + b.y + b.z + b.w;
    unsigned suf = sl;
    #pragma unroll
    for (int off = 1; off < 64; off <<= 1) {
        unsigned t = __shfl_down(suf, off);
        suf += (lane + off < 64) ? t : 0u;
    }
    bool qual = (suf >= (unsigned)need) && (suf - sl < (unsigned)need);
    unsigned long long mask = __ballot(qual);
    int src = (int)__builtin_ctzll(mask);

    unsigned bb0 = b.x, bb1 = b.y, bb2 = b.z, bb3 = b.w;
    unsigned cum = suf - sl;
    int myB = 0; unsigned myAbove = 0, myEq = 0;
    // scan own 4 bins from high (4l+3) to low (4l)
    if (cum + bb3 >= (unsigned)need) { myB = lane * 4 + 3; myAbove = cum; myEq = bb3; }
    else {
        cum += bb3;
        if (cum + bb2 >= (unsigned)need) { myB = lane * 4 + 2; myAbove = cum; myEq = bb2; }
        else {
            cum += bb2;
            if (cum + bb1 >= (unsigned)need) { myB = lane * 4 + 1; myAbove = cum; myEq = bb1; }
            else {
                cum += bb1;
                if (cum + bb0 >= (unsigned)need) { myB = lane * 4 + 0; myAbove = cum; myEq = bb0; }
            }
        }
    }
    B = __shfl(myB, src);
    needRem = need - (int)__shfl((int)myAbove, src);
    eqc = (int)__shfl((int)myEq, src);
}

// ---------------- attention v2: block = (16 q-rows, 1 head), 4 waves ----------------
__global__ __launch_bounds__(256, 2) void attn2(const __hip_bfloat16* __restrict__ qhi,
                                                const __hip_bfloat16* __restrict__ qlo,
                                                const __hip_bfloat16* __restrict__ khi,
                                                const __hip_bfloat16* __restrict__ klo,
                                                const float* __restrict__ vh,
                                                __hip_bfloat16* __restrict__ yb)
{
    __shared__ unsigned short su[16][2048];   // 64 KB: quantized score keys (0 = masked)
    __shared__ unsigned hist[4][256];         // per-wave histograms
    __shared__ unsigned short klist[16][128]; // kept key indices per row

    const int q0 = blockIdx.x * 16;
    const int h = blockIdx.y;
    const int tid = threadIdx.x, lane = tid & 63, wv = tid >> 6;
    const int ntiles = (q0 + 16 + 63) >> 6;
    const int SB = ntiles * 64;               // scan bound (mult of 64)
    const size_t hb = (size_t)h * S_LEN;

    // ---- Q fragments (rows q0..q0+15), split bf16 hi/lo ----
    const int fr = lane & 15;
    const int ak = (lane >> 4) * 8;
    const short* qh_ = (const short*)qhi + (hb + q0 + fr) * HD;
    const short* ql_ = (const short*)qlo + (hb + q0 + fr) * HD;
    s16x8 qa_h0 = *(const s16x8*)(qh_ + ak);
    s16x8 qa_h1 = *(const s16x8*)(qh_ + ak + 32);
    s16x8 qa_l0 = *(const s16x8*)(ql_ + ak);
    s16x8 qa_l1 = *(const s16x8*)(ql_ + ak + 32);

    // ---- scores via MFMA (3-term split-bf16), quantize to u16 keys ----
    for (int t = wv; t < ntiles; t += 4) {
        const int k0 = t * 64;
        #pragma unroll
        for (int cb = 0; cb < 4; ++cb) {
            const int key = k0 + cb * 16 + fr;
            const short* kh_ = (const short*)khi + (hb + key) * HD;
            const short* kl_ = (const short*)klo + (hb + key) * HD;
            s16x8 b_h0 = *(const s16x8*)(kh_ + ak);
            s16x8 b_h1 = *(const s16x8*)(kh_ + ak + 32);
            s16x8 b_l0 = *(const s16x8*)(kl_ + ak);
            s16x8 b_l1 = *(const s16x8*)(kl_ + ak + 32);
            f32x4 acc = {};
            acc = __builtin_amdgcn_mfma_f32_16x16x32_bf16(qa_h0, b_h0, acc, 0, 0, 0);
            acc = __builtin_amdgcn_mfma_f32_16x16x32_bf16(qa_h1, b_h1, acc, 0, 0, 0);
            acc = __builtin_amdgcn_mfma_f32_16x16x32_bf16(qa_h0, b_l0, acc, 0, 0, 0);
            acc = __builtin_amdgcn_mfma_f32_16x16x32_bf16(qa_h1, b_l1, acc, 0, 0, 0);
            acc = __builtin_amdgcn_mfma_f32_16x16x32_bf16(qa_l0, b_h0, acc, 0, 0, 0);
            acc = __builtin_amdgcn_mfma_f32_16x16x32_bf16(qa_l1, b_h1, acc, 0, 0, 0);
            #pragma unroll
            for (int j = 0; j < 4; ++j) {
                const int row = (lane >> 4) * 4 + j;
                float s = acc[j] * 0.125f;
                int ku = 0;
                if (key <= q0 + row) {
                    ku = 1 + (int)((s + KOFF) * KSCALE);
                    ku = ku < 1 ? 1 : (ku > 65535 ? 65535 : ku);
                }
                su[row][key] = (unsigned short)ku;
            }
        }
    }
    __syncthreads();

    // ---- per-wave rows: select + softmax + PV ----
    const int nchT = (SB + 255) >> 8;

    for (int r8 = 0; r8 < 4; ++r8) {
        const int row = wv * 4 + r8;
        const int q = q0 + row;
        const int need = (q + 1 < TOPK) ? q + 1 : TOPK;

        // pass 1: hi-byte histogram (wave-local)
        *(uint4*)&hist[wv][lane * 4] = make_uint4(0u, 0u, 0u, 0u);
        for (int c = 0; c < nchT; ++c) {
            const int base = (c << 8) + lane * 4;
            if (base < SB) {
                unsigned long long w8 = *(const unsigned long long*)&su[row][base];
                unsigned k0_ = (unsigned)(w8 & 0xffff), k1_ = (unsigned)((w8 >> 16) & 0xffff);
                unsigned k2_ = (unsigned)((w8 >> 32) & 0xffff), k3_ = (unsigned)((w8 >> 48) & 0xffff);
                if (k0_) atomicAdd(&hist[wv][k0_ >> 8], 1u);
                if (k1_) atomicAdd(&hist[wv][k1_ >> 8], 1u);
                if (k2_) atomicAdd(&hist[wv][k2_ >> 8], 1u);
                if (k3_) atomicAdd(&hist[wv][k3_ >> 8], 1u);
            }
        }
        __asm__ volatile("s_waitcnt lgkmcnt(0)" ::: "memory");
        int B1, need2, eqc1;
        find_byte(hist[wv], need, lane, B1, need2, eqc1);

        // pass 2: lo-byte histogram among hi==B1
        *(uint4*)&hist[wv][lane * 4] = make_uint4(0u, 0u, 0u, 0u);
        for (int c = 0; c < nchT; ++c) {
            const int base = (c << 8) + lane * 4;
            if (base < SB) {
                unsigned long long w8 = *(const unsigned long long*)&su[row][base];
                unsigned k0_ = (unsigned)(w8 & 0xffff), k1_ = (unsigned)((w8 >> 16) & 0xffff);
                unsigned k2_ = (unsigned)((w8 >> 32) & 0xffff), k3_ = (unsigned)((w8 >> 48) & 0xffff);
                if (k0_ && (k0_ >> 8) == (unsigned)B1) atomicAdd(&hist[wv][k0_ & 255u], 1u);
                if (k1_ && (k1_ >> 8) == (unsigned)B1) atomicAdd(&hist[wv][k1_ & 255u], 1u);
                if (k2_ && (k2_ >> 8) == (unsigned)B1) atomicAdd(&hist[wv][k2_ & 255u], 1u);
                if (k3_ && (k3_ >> 8) == (unsigned)B1) atomicAdd(&hist[wv][k3_ & 255u], 1u);
            }
        }
        __asm__ volatile("s_waitcnt lgkmcnt(0)" ::: "memory");
        int B2, takeEq, eqc2;
        find_byte(hist[wv], need2, lane, B2, takeEq, eqc2);

        const unsigned T = ((unsigned)B1 << 8) | (unsigned)B2;
        const int gtTot = need - takeEq;
        const bool tieEasy = (takeEq == eqc2);

        // pass 3: compaction (store key INDICES)
        int gbase = 0, te = 0;
        for (int c = 0; c < nchT; ++c) {
            const int base = (c << 8) + lane * 4;
            const bool g = base < SB;
            unsigned long long w8 = g ? *(const unsigned long long*)&su[row][base] : 0ull;
            unsigned kk[4];
            kk[0] = (unsigned)(w8 & 0xffff); kk[1] = (unsigned)((w8 >> 16) & 0xffff);
            kk[2] = (unsigned)((w8 >> 32) & 0xffff); kk[3] = (unsigned)((w8 >> 48) & 0xffff);
            bool f0, f1, f2, f3;
            if (tieEasy) { f0 = kk[0] >= T; f1 = kk[1] >= T; f2 = kk[2] >= T; f3 = kk[3] >= T; }
            else         { f0 = kk[0] >  T; f1 = kk[1] >  T; f2 = kk[2] >  T; f3 = kk[3] >  T; }
            unsigned cl = (unsigned)f0 + f1 + f2 + f3;
            unsigned inc = wave_prefix_incl(cl, lane);
            int slot = gbase + (int)(inc - cl);
            if (f0) klist[row][slot++] = (unsigned short)(base + 0);
            if (f1) klist[row][slot++] = (unsigned short)(base + 1);
            if (f2) klist[row][slot++] = (unsigned short)(base + 2);
            if (f3) klist[row][slot++] = (unsigned short)(base + 3);
            gbase += (int)__shfl((int)inc, 63);
            if (!tieEasy) {
                #pragma unroll
                for (int j = 0; j < 4; ++j) {
                    bool tj = g && (kk[j] == T);
                    unsigned long long bal = __ballot(tj);
                    int r = te + (int)__popcll(bal & ((1ull << lane) - 1ull));
                    if (tj && r < takeEq) klist[row][gtTot + r] = (unsigned short)(base + j);
                    te += (int)__popcll(bal);
                }
            }
        }

        // PV: softmax weights from quantized keys, coalesced V gathers
        int kk0 = 0, kk1 = 0; float pp0 = 0.f, pp1 = 0.f;
        if (lane < need) {
            kk0 = klist[row][lane];
            pp0 = __expf(((float)su[row][kk0] - 0.5f) * KINV - KOFF);
        }
        if (64 + lane < need) {
            kk1 = klist[row][64 + lane];
            pp1 = __expf(((float)su[row][kk1] - 0.5f) * KINV - KOFF);
        }
        const float* vbase = vh + hb * HD;
        float acc = 0.f, psum = 0.f;
        const int n0 = need < 64 ? need : 64;
        #pragma unroll 8
        for (int i = 0; i < n0; ++i) {
            float p = __shfl(pp0, i);
            int k = __shfl(kk0, i);
            psum += p;
            acc += p * vbase[(size_t)k * HD + lane];
        }
        const int n1 = need - 64;
        #pragma unroll 8
        for (int i = 0; i < n1; ++i) {
            float p = __shfl(pp1, i);
            int k = __shfl(kk1, i);
            psum += p;
            acc += p * vbase[(size_t)k * HD + lane];
        }
        yb[(size_t)q * C_DIM + h * HD + lane] = __float2bfloat16(acc / psum);
    }
}

// ---------------- launch ----------------
extern "C" void kernel_launch(void* const* d_in, const int* in_sizes, int n_in,
                              void* d_out, int out_size, void* d_ws, size_t ws_size,
                              hipStream_t stream)
{
    const float* x      = (const float*)d_in[0];
    const float* w_qkv  = (const float*)d_in[1];
    const float* w_proj = (const float*)d_in[2];
    float* out = (float*)d_out;

    char* ws = (char*)d_ws;
    size_t off = 0;
    auto alloc = [&](size_t bytes) -> void* {
        void* p = ws + off;
        off += (bytes + 255) & ~(size_t)255;
        return p;
    };
    __hip_bfloat16* xb  = (__hip_bfloat16*)alloc((size_t)S_LEN * C_DIM * 2);
    __hip_bfloat16* wqb = (__hip_bfloat16*)alloc((size_t)3 * C_DIM * C_DIM * 2);
    __hip_bfloat16* wpb = (__hip_bfloat16*)alloc((size_t)C_DIM * C_DIM * 2);
    float* qkvf = (float*)alloc((size_t)S_LEN * 3 * C_DIM * 4);
    __hip_bfloat16* qhi = (__hip_bfloat16*)alloc((size_t)NH * S_LEN * HD * 2);
    __hip_bfloat16* qlo = (__hip_bfloat16*)alloc((size_t)NH * S_LEN * HD * 2);
    __hip_bfloat16* khi = (__hip_bfloat16*)alloc((size_t)NH * S_LEN * HD * 2);
    __hip_bfloat16* klo = (__hip_bfloat16*)alloc((size_t)NH * S_LEN * HD * 2);
    float* vh = (float*)alloc((size_t)NH * S_LEN * HD * 4);
    __hip_bfloat16* yb = (__hip_bfloat16*)alloc((size_t)S_LEN * C_DIM * 2);

    int n1 = S_LEN * C_DIM, n2 = 3 * C_DIM * C_DIM, n3 = C_DIM * C_DIM;
    cvt_f32_bf16<<<n1 / 4 / 256, 256, 0, stream>>>(x, xb, n1);
    cvt_f32_bf16<<<n2 / 4 / 256, 256, 0, stream>>>(w_qkv, wqb, n2);
    cvt_f32_bf16<<<n3 / 4 / 256, 256, 0, stream>>>(w_proj, wpb, n3);

    gemm_bt<<<dim3(3 * C_DIM / 128, S_LEN / 128), 256, 0, stream>>>(xb, wqb, qkvf, S_LEN, 3 * C_DIM, C_DIM);

    rope_norm<<<NH * S_LEN / 4, 256, 0, stream>>>(qkvf, qhi, qlo, khi, klo, vh);

    attn2<<<dim3(S_LEN / 16, NH), 256, 0, stream>>>(qhi, qlo, khi, klo, vh, yb);

    gemm_bt<<<dim3(C_DIM / 128, S_LEN / 128), 256, 0, stream>>>(yb, wpb, out, S_LEN, C_DIM, C_DIM);
}

// Round 4
// 338.810 us; speedup vs baseline: 8.3609x; 2.0386x over previous
//
#include <hip/hip_runtime.h>
#include <hip/hip_bf16.h>
#include <math.h>

#define S_LEN 2048
#define C_DIM 1024
#define NH    16
#define HD    64
#define TOPK  128

typedef __attribute__((ext_vector_type(8))) short s16x8;
typedef __attribute__((ext_vector_type(4))) float f32x4;

#define KSCALE 250000.0f
#define KINV   (1.0f / 250000.0f)
#define KOFF   0.13f
#define SUW    2056   // su row stride (u16 elems): bank shift 4/row, breaks write conflicts

// ---------------- f32 -> bf16 convert ----------------
__global__ void cvt_f32_bf16(const float* __restrict__ in, __hip_bfloat16* __restrict__ out, int n) {
    int idx = (blockIdx.x * blockDim.x + threadIdx.x) * 4;
    if (idx + 3 < n) {
        float4 v = *(const float4*)(in + idx);
        out[idx + 0] = __float2bfloat16(v.x);
        out[idx + 1] = __float2bfloat16(v.y);
        out[idx + 2] = __float2bfloat16(v.z);
        out[idx + 3] = __float2bfloat16(v.w);
    }
}

// ---------------- GEMM (m97 structure): C[M][N] = A[M][K] * B[N][K]^T ----------------
typedef const __attribute__((address_space(1))) unsigned int* gp32;
typedef __attribute__((address_space(3))) unsigned int* lp32;

__global__ __launch_bounds__(256) void gemm_bt(const __hip_bfloat16* __restrict__ A,
                                               const __hip_bfloat16* __restrict__ B,
                                               float* __restrict__ C,
                                               int M, int N, int K)
{
    __shared__ short As[128 * 32];
    __shared__ short Bs[128 * 32];
    const int bm = blockIdx.y * 128;
    const int bn = blockIdx.x * 128;
    const int tid = threadIdx.x;
    const int lane = tid & 63;
    const int wave = tid >> 6;
    const int wm = (wave >> 1) * 64;
    const int wn = (wave & 1) * 64;

    f32x4 acc[4][4] = {};

    const int srow = tid >> 2;
    const int scol = (tid & 3) * 8;
    const int fr = lane & 15;
    const int fk = (lane >> 4) * 8;

    const short* Ab = (const short*)A;
    const short* Bb = (const short*)B;

    for (int k0 = 0; k0 < K; k0 += 32) {
        __syncthreads();
        __builtin_amdgcn_global_load_lds((gp32)(Ab + (size_t)(bm + srow) * K + k0 + scol),
                                         (lp32)((char*)As + tid * 16), 16, 0, 0);
        __builtin_amdgcn_global_load_lds((gp32)(Ab + (size_t)(bm + 64 + srow) * K + k0 + scol),
                                         (lp32)((char*)As + 4096 + tid * 16), 16, 0, 0);
        __builtin_amdgcn_global_load_lds((gp32)(Bb + (size_t)(bn + srow) * K + k0 + scol),
                                         (lp32)((char*)Bs + tid * 16), 16, 0, 0);
        __builtin_amdgcn_global_load_lds((gp32)(Bb + (size_t)(bn + 64 + srow) * K + k0 + scol),
                                         (lp32)((char*)Bs + 4096 + tid * 16), 16, 0, 0);
        __syncthreads();

        s16x8 af[4], bfr[4];
        #pragma unroll
        for (int m = 0; m < 4; ++m) af[m]  = *(const s16x8*)&As[(wm + m * 16 + fr) * 32 + fk];
        #pragma unroll
        for (int n = 0; n < 4; ++n) bfr[n] = *(const s16x8*)&Bs[(wn + n * 16 + fr) * 32 + fk];
        #pragma unroll
        for (int m = 0; m < 4; ++m)
            #pragma unroll
            for (int n = 0; n < 4; ++n)
                acc[m][n] = __builtin_amdgcn_mfma_f32_16x16x32_bf16(af[m], bfr[n], acc[m][n], 0, 0, 0);
    }

    const int cr = (lane >> 4) * 4;
    const int cc = lane & 15;
    #pragma unroll
    for (int m = 0; m < 4; ++m)
        #pragma unroll
        for (int n = 0; n < 4; ++n)
            #pragma unroll
            for (int j = 0; j < 4; ++j) {
                int row = bm + wm + m * 16 + cr + j;
                int col = bn + wn + n * 16 + cc;
                C[(size_t)row * N + col] = acc[m][n][j];
            }
}

// ---------------- RoPE + L2-normalize + head split (bf16 hi/lo q,k; bf16 v) ----------
__global__ __launch_bounds__(256) void rope_norm(const float* __restrict__ qkv,
                                                 __hip_bfloat16* __restrict__ qhi,
                                                 __hip_bfloat16* __restrict__ qlo,
                                                 __hip_bfloat16* __restrict__ khi,
                                                 __hip_bfloat16* __restrict__ klo,
                                                 __hip_bfloat16* __restrict__ vh)
{
    const int gw = blockIdx.x * 4 + (threadIdx.x >> 6);
    const int lane = threadIdx.x & 63;
    const int h = gw >> 11;
    const int s = gw & 2047;
    const float* base = qkv + (size_t)s * (3 * C_DIM);
    float qx = base[h * HD + lane];
    float kx = base[C_DIM + h * HD + lane];
    float vx = base[2 * C_DIM + h * HD + lane];

    const int i = lane >> 1;
    const float invf = expf(-(float)(2 * i) * (9.210340371976184f / 64.f));
    const float ang = (float)s * invf;
    float sn, cs;
    sincosf(ang, &sn, &cs);
    float qp = __shfl_xor(qx, 1);
    float kp = __shfl_xor(kx, 1);
    const float sgn = (lane & 1) ? 1.f : -1.f;
    float qr = qx * cs + sgn * qp * sn;
    float kr = kx * cs + sgn * kp * sn;

    float s2q = qr * qr, s2k = kr * kr;
    #pragma unroll
    for (int off = 32; off > 0; off >>= 1) {
        s2q += __shfl_xor(s2q, off);
        s2k += __shfl_xor(s2k, off);
    }
    qr = qr / fmaxf(sqrtf(s2q), 1e-12f);
    kr = kr / fmaxf(sqrtf(s2k), 1e-12f);

    size_t o = ((size_t)h * S_LEN + s) * HD + lane;
    __hip_bfloat16 qh_ = __float2bfloat16(qr);
    __hip_bfloat16 kh_ = __float2bfloat16(kr);
    qhi[o] = qh_; qlo[o] = __float2bfloat16(qr - __bfloat162float(qh_));
    khi[o] = kh_; klo[o] = __float2bfloat16(kr - __bfloat162float(kh_));
    vh[o] = __float2bfloat16(vx);
}

// ---------------- wave helpers ----------------
__device__ __forceinline__ unsigned wave_prefix_incl(unsigned v, int lane) {
    #pragma unroll
    for (int off = 1; off < 64; off <<= 1) {
        unsigned t = __shfl_up(v, off);
        v += (lane >= off) ? t : 0u;
    }
    return v;
}

__device__ __forceinline__ void find_byte(const unsigned* hist256, int need, int lane,
                                          int& B, int& needRem, int& eqc)
{
    uint4 b = *(const uint4*)&hist256[lane * 4];
    unsigned sl = b.x + b.y + b.z + b.w;
    unsigned suf = sl;
    #pragma unroll
    for (int off = 1; off < 64; off <<= 1) {
        unsigned t = __shfl_down(suf, off);
        suf += (lane + off < 64) ? t : 0u;
    }
    bool qual = (suf >= (unsigned)need) && (suf - sl < (unsigned)need);
    unsigned long long mask = __ballot(qual);
    int src = (int)__builtin_ctzll(mask);

    unsigned bb0 = b.x, bb1 = b.y, bb2 = b.z, bb3 = b.w;
    unsigned cum = suf - sl;
    int myB = 0; unsigned myAbove = 0, myEq = 0;
    if (cum + bb3 >= (unsigned)need) { myB = lane * 4 + 3; myAbove = cum; myEq = bb3; }
    else {
        cum += bb3;
        if (cum + bb2 >= (unsigned)need) { myB = lane * 4 + 2; myAbove = cum; myEq = bb2; }
        else {
            cum += bb2;
            if (cum + bb1 >= (unsigned)need) { myB = lane * 4 + 1; myAbove = cum; myEq = bb1; }
            else {
                cum += bb1;
                if (cum + bb0 >= (unsigned)need) { myB = lane * 4 + 0; myAbove = cum; myEq = bb0; }
            }
        }
    }
    B = __shfl(myB, src);
    needRem = need - (int)__shfl((int)myAbove, src);
    eqc = (int)__shfl((int)myEq, src);
}

// ---------------- attention v3: block = (8 q-rows, 1 head), 4 waves, 4 blocks/CU ----
__global__ __launch_bounds__(256, 4) void attn3(const __hip_bfloat16* __restrict__ qhi,
                                                const __hip_bfloat16* __restrict__ qlo,
                                                const __hip_bfloat16* __restrict__ khi,
                                                const __hip_bfloat16* __restrict__ klo,
                                                const __hip_bfloat16* __restrict__ vhb,
                                                __hip_bfloat16* __restrict__ yb)
{
    __shared__ unsigned short su[8][SUW];     // ~33 KB quantized keys (0 = masked)
    __shared__ unsigned hist[4][256];         // per-wave histograms
    __shared__ unsigned short klist[8][TOPK];

    const int q0 = blockIdx.x * 8;
    const int h = blockIdx.y;
    const int tid = threadIdx.x, lane = tid & 63, wv = tid >> 6;
    const int ntiles = (q0 + 8 + 63) >> 6;
    const int SB = ntiles * 64;
    const size_t hb = (size_t)h * S_LEN;

    // ---- Q fragments: rows q0..q0+7 duplicated across fr 0-7 / 8-15 ----
    const int fr = lane & 15;
    const int ak = (lane >> 4) * 8;
    const short* qp_h = (const short*)qhi + (hb + q0 + (fr & 7)) * HD;
    const short* qp_l = (const short*)qlo + (hb + q0 + (fr & 7)) * HD;
    s16x8 qa_h0 = *(const s16x8*)(qp_h + ak);
    s16x8 qa_h1 = *(const s16x8*)(qp_h + ak + 32);
    s16x8 qa_l0 = *(const s16x8*)(qp_l + ak);
    s16x8 qa_l1 = *(const s16x8*)(qp_l + ak + 32);

    // ---- scores via MFMA (split-bf16), quantize to u16 keys ----
    for (int t = wv; t < ntiles; t += 4) {
        const int k0 = t * 64;
        #pragma unroll
        for (int cb = 0; cb < 4; ++cb) {
            const int key = k0 + cb * 16 + fr;
            const short* kh_ = (const short*)khi + (hb + key) * HD;
            const short* kl_ = (const short*)klo + (hb + key) * HD;
            s16x8 b_h0 = *(const s16x8*)(kh_ + ak);
            s16x8 b_h1 = *(const s16x8*)(kh_ + ak + 32);
            s16x8 b_l0 = *(const s16x8*)(kl_ + ak);
            s16x8 b_l1 = *(const s16x8*)(kl_ + ak + 32);
            f32x4 acc = {};
            acc = __builtin_amdgcn_mfma_f32_16x16x32_bf16(qa_h0, b_h0, acc, 0, 0, 0);
            acc = __builtin_amdgcn_mfma_f32_16x16x32_bf16(qa_h1, b_h1, acc, 0, 0, 0);
            acc = __builtin_amdgcn_mfma_f32_16x16x32_bf16(qa_h0, b_l0, acc, 0, 0, 0);
            acc = __builtin_amdgcn_mfma_f32_16x16x32_bf16(qa_h1, b_l1, acc, 0, 0, 0);
            acc = __builtin_amdgcn_mfma_f32_16x16x32_bf16(qa_l0, b_h0, acc, 0, 0, 0);
            acc = __builtin_amdgcn_mfma_f32_16x16x32_bf16(qa_l1, b_h1, acc, 0, 0, 0);
            #pragma unroll
            for (int j = 0; j < 4; ++j) {
                const int rowD = (lane >> 4) * 4 + j;
                if (rowD < 8) {
                    float s = acc[j] * 0.125f;
                    int ku = 0;
                    if (key <= q0 + rowD) {
                        ku = 1 + (int)((s + KOFF) * KSCALE);
                        ku = ku < 1 ? 1 : (ku > 65535 ? 65535 : ku);
                    }
                    su[rowD][key] = (unsigned short)ku;
                }
            }
        }
    }
    __syncthreads();

    // ---- per-wave: 2 rows, select + softmax + PV ----
    const int nchT = (SB + 255) >> 8;

    for (int r8 = 0; r8 < 2; ++r8) {
        const int row = wv * 2 + r8;
        const int q = q0 + row;
        const int need = (q + 1 < TOPK) ? q + 1 : TOPK;

        if (q < TOPK) {
            // trivial: keep everything
            for (int s = lane; s < need; s += 64) klist[row][s] = (unsigned short)s;
            for (int s = need + lane; s < TOPK; s += 64) klist[row][s] = 0;
        } else {
            // pass 1: hi-byte histogram (wave-local)
            *(uint4*)&hist[wv][lane * 4] = make_uint4(0u, 0u, 0u, 0u);
            for (int c = 0; c < nchT; ++c) {
                const int base = (c << 8) + lane * 4;
                if (base < SB) {
                    unsigned long long w8 = *(const unsigned long long*)&su[row][base];
                    unsigned k0_ = (unsigned)(w8 & 0xffff), k1_ = (unsigned)((w8 >> 16) & 0xffff);
                    unsigned k2_ = (unsigned)((w8 >> 32) & 0xffff), k3_ = (unsigned)((w8 >> 48) & 0xffff);
                    if (k0_) atomicAdd(&hist[wv][k0_ >> 8], 1u);
                    if (k1_) atomicAdd(&hist[wv][k1_ >> 8], 1u);
                    if (k2_) atomicAdd(&hist[wv][k2_ >> 8], 1u);
                    if (k3_) atomicAdd(&hist[wv][k3_ >> 8], 1u);
                }
            }
            __asm__ volatile("s_waitcnt lgkmcnt(0)" ::: "memory");
            int B1, need2, eqc1;
            find_byte(hist[wv], need, lane, B1, need2, eqc1);

            // pass 2: lo-byte histogram among hi==B1
            *(uint4*)&hist[wv][lane * 4] = make_uint4(0u, 0u, 0u, 0u);
            for (int c = 0; c < nchT; ++c) {
                const int base = (c << 8) + lane * 4;
                if (base < SB) {
                    unsigned long long w8 = *(const unsigned long long*)&su[row][base];
                    unsigned k0_ = (unsigned)(w8 & 0xffff), k1_ = (unsigned)((w8 >> 16) & 0xffff);
                    unsigned k2_ = (unsigned)((w8 >> 32) & 0xffff), k3_ = (unsigned)((w8 >> 48) & 0xffff);
                    if (k0_ && (k0_ >> 8) == (unsigned)B1) atomicAdd(&hist[wv][k0_ & 255u], 1u);
                    if (k1_ && (k1_ >> 8) == (unsigned)B1) atomicAdd(&hist[wv][k1_ & 255u], 1u);
                    if (k2_ && (k2_ >> 8) == (unsigned)B1) atomicAdd(&hist[wv][k2_ & 255u], 1u);
                    if (k3_ && (k3_ >> 8) == (unsigned)B1) atomicAdd(&hist[wv][k3_ & 255u], 1u);
                }
            }
            __asm__ volatile("s_waitcnt lgkmcnt(0)" ::: "memory");
            int B2, takeEq, eqc2;
            find_byte(hist[wv], need2, lane, B2, takeEq, eqc2);

            const unsigned T = ((unsigned)B1 << 8) | (unsigned)B2;
            const int gtTot = need - takeEq;
            const bool tieEasy = (takeEq == eqc2);

            // pass 3: compaction
            int gbase = 0, te = 0;
            for (int c = 0; c < nchT; ++c) {
                const int base = (c << 8) + lane * 4;
                const bool g = base < SB;
                unsigned long long w8 = g ? *(const unsigned long long*)&su[row][base] : 0ull;
                unsigned kk[4];
                kk[0] = (unsigned)(w8 & 0xffff); kk[1] = (unsigned)((w8 >> 16) & 0xffff);
                kk[2] = (unsigned)((w8 >> 32) & 0xffff); kk[3] = (unsigned)((w8 >> 48) & 0xffff);
                bool f0, f1, f2, f3;
                if (tieEasy) { f0 = kk[0] >= T; f1 = kk[1] >= T; f2 = kk[2] >= T; f3 = kk[3] >= T; }
                else         { f0 = kk[0] >  T; f1 = kk[1] >  T; f2 = kk[2] >  T; f3 = kk[3] >  T; }
                unsigned cl = (unsigned)f0 + f1 + f2 + f3;
                unsigned inc = wave_prefix_incl(cl, lane);
                int slot = gbase + (int)(inc - cl);
                if (f0) klist[row][slot++] = (unsigned short)(base + 0);
                if (f1) klist[row][slot++] = (unsigned short)(base + 1);
                if (f2) klist[row][slot++] = (unsigned short)(base + 2);
                if (f3) klist[row][slot++] = (unsigned short)(base + 3);
                gbase += (int)__shfl((int)inc, 63);
                if (!tieEasy) {
                    #pragma unroll
                    for (int j = 0; j < 4; ++j) {
                        bool tj = g && (kk[j] == T);
                        unsigned long long bal = __ballot(tj);
                        int r = te + (int)__popcll(bal & ((1ull << lane) - 1ull));
                        if (tj && r < takeEq) klist[row][gtTot + r] = (unsigned short)(base + j);
                        te += (int)__popcll(bal);
                    }
                }
            }
        }
        __asm__ volatile("s_waitcnt lgkmcnt(0)" ::: "memory");

        // ---- PV: lane = (key-slot g=lane>>3, dim-slice d0=(lane&7)*8), bf16 V ----
        const int g = lane >> 3;
        const int d0 = (lane & 7) * 8;
        const short* vb = (const short*)vhb + hb * HD;
        float acc8[8] = {0.f, 0.f, 0.f, 0.f, 0.f, 0.f, 0.f, 0.f};
        float psum = 0.f;

        #pragma unroll
        for (int half = 0; half < 2; ++half) {
            int kk[8]; float pp[8];
            #pragma unroll
            for (int b = 0; b < 8; ++b) {
                const int slot = (half * 8 + b) * 8 + g;
                const int k = klist[row][slot];
                kk[b] = k;
                pp[b] = (slot < need) ? __expf(((float)su[row][k] - 0.5f) * KINV - KOFF) : 0.f;
            }
            s16x8 vv[8];
            #pragma unroll
            for (int b = 0; b < 8; ++b) vv[b] = *(const s16x8*)(vb + (size_t)kk[b] * HD + d0);
            #pragma unroll
            for (int b = 0; b < 8; ++b) {
                psum += pp[b];
                #pragma unroll
                for (int j = 0; j < 8; ++j) {
                    unsigned short us = (unsigned short)vv[b][j];
                    float vf = __bfloat162float(*reinterpret_cast<__hip_bfloat16*>(&us));
                    acc8[j] += pp[b] * vf;
                }
            }
        }

        #pragma unroll
        for (int off = 8; off < 64; off <<= 1) {
            psum += __shfl_xor(psum, off);
            #pragma unroll
            for (int j = 0; j < 8; ++j) acc8[j] += __shfl_xor(acc8[j], off);
        }

        if (lane < 8) {
            const float inv = 1.0f / psum;
            s16x8 r;
            #pragma unroll
            for (int j = 0; j < 8; ++j) {
                __hip_bfloat16 bf = __float2bfloat16(acc8[j] * inv);
                r[j] = *reinterpret_cast<short*>(&bf);
            }
            *(s16x8*)((short*)yb + (size_t)q * C_DIM + h * HD + lane * 8) = r;
        }
    }
}

// ---------------- launch ----------------
extern "C" void kernel_launch(void* const* d_in, const int* in_sizes, int n_in,
                              void* d_out, int out_size, void* d_ws, size_t ws_size,
                              hipStream_t stream)
{
    const float* x      = (const float*)d_in[0];
    const float* w_qkv  = (const float*)d_in[1];
    const float* w_proj = (const float*)d_in[2];
    float* out = (float*)d_out;

    char* ws = (char*)d_ws;
    size_t off = 0;
    auto alloc = [&](size_t bytes) -> void* {
        void* p = ws + off;
        off += (bytes + 255) & ~(size_t)255;
        return p;
    };
    __hip_bfloat16* xb  = (__hip_bfloat16*)alloc((size_t)S_LEN * C_DIM * 2);
    __hip_bfloat16* wqb = (__hip_bfloat16*)alloc((size_t)3 * C_DIM * C_DIM * 2);
    __hip_bfloat16* wpb = (__hip_bfloat16*)alloc((size_t)C_DIM * C_DIM * 2);
    float* qkvf = (float*)alloc((size_t)S_LEN * 3 * C_DIM * 4);
    __hip_bfloat16* qhi = (__hip_bfloat16*)alloc((size_t)NH * S_LEN * HD * 2);
    __hip_bfloat16* qlo = (__hip_bfloat16*)alloc((size_t)NH * S_LEN * HD * 2);
    __hip_bfloat16* khi = (__hip_bfloat16*)alloc((size_t)NH * S_LEN * HD * 2);
    __hip_bfloat16* klo = (__hip_bfloat16*)alloc((size_t)NH * S_LEN * HD * 2);
    __hip_bfloat16* vhb = (__hip_bfloat16*)alloc((size_t)NH * S_LEN * HD * 2);
    __hip_bfloat16* yb  = (__hip_bfloat16*)alloc((size_t)S_LEN * C_DIM * 2);

    int n1 = S_LEN * C_DIM, n2 = 3 * C_DIM * C_DIM, n3 = C_DIM * C_DIM;
    cvt_f32_bf16<<<n1 / 4 / 256, 256, 0, stream>>>(x, xb, n1);
    cvt_f32_bf16<<<n2 / 4 / 256, 256, 0, stream>>>(w_qkv, wqb, n2);
    cvt_f32_bf16<<<n3 / 4 / 256, 256, 0, stream>>>(w_proj, wpb, n3);

    gemm_bt<<<dim3(3 * C_DIM / 128, S_LEN / 128), 256, 0, stream>>>(xb, wqb, qkvf, S_LEN, 3 * C_DIM, C_DIM);

    rope_norm<<<NH * S_LEN / 4, 256, 0, stream>>>(qkvf, qhi, qlo, khi, klo, vhb);

    attn3<<<dim3(S_LEN / 8, NH), 256, 0, stream>>>(qhi, qlo, khi, klo, vhb, yb);

    gemm_bt<<<dim3(C_DIM / 128, S_LEN / 128), 256, 0, stream>>>(yb, wpb, out, S_LEN, C_DIM, C_DIM);
}